// Round 6
// baseline (363.520 us; speedup 1.0000x reference)
//
#include <hip/hip_runtime.h>

typedef unsigned short u16;
typedef unsigned int u32;

#define NB 4
#define NN 512
#define ND 256
#define NH 256
#define TI 4
#define NBLK 512

typedef __attribute__((ext_vector_type(8))) short short8;
typedef __attribute__((ext_vector_type(4))) float f32x4;

__device__ __forceinline__ u16 bfq(float f) {
    u32 t; __builtin_memcpy(&t, &f, 4);
    u32 r = (t + 0x7FFFu + ((t >> 16) & 1u)) >> 16;
    return (u16)r;
}

__device__ __forceinline__ float waveReduceSum(float v) {
#pragma unroll
    for (int o = 32; o > 0; o >>= 1) v += __shfl_down(v, o);
    return v;
}

// block-wide sum-reduce of TWO float4s (8 values) across 8 waves; 2 barriers total.
__device__ __forceinline__ void blockReduce8(float4& va, float4& vb, float4* red) {
#pragma unroll
    for (int o = 32; o > 0; o >>= 1) {
        va.x += __shfl_down(va.x, o); va.y += __shfl_down(va.y, o);
        va.z += __shfl_down(va.z, o); va.w += __shfl_down(va.w, o);
        vb.x += __shfl_down(vb.x, o); vb.y += __shfl_down(vb.y, o);
        vb.z += __shfl_down(vb.z, o); vb.w += __shfl_down(vb.w, o);
    }
    int wid = threadIdx.x >> 6;
    __syncthreads();
    if ((threadIdx.x & 63) == 0) { red[2 * wid] = va; red[2 * wid + 1] = vb; }
    __syncthreads();
    float4 ra = red[0], rb = red[1];
#pragma unroll
    for (int w = 1; w < 8; ++w) {
        float4 ua = red[2 * w], ub = red[2 * w + 1];
        ra.x += ua.x; ra.y += ua.y; ra.z += ua.z; ra.w += ua.w;
        rb.x += ub.x; rb.y += ub.y; rb.z += ub.z; rb.w += ub.w;
    }
    va = ra; vb = rb;
}

// ---- software grid barrier (all NBLK blocks co-resident by construction) ----
// arrive: block-drain (__syncthreads inserts vmcnt drain) then agent-release add
//         (flushes this XCD's L2). Local work may be placed between arrive/wait.
// wait:   agent-acquire poll (invalidates stale L1/L2) then block barrier + fence.
__device__ __forceinline__ void gbar_arrive(u32* c) {
    __syncthreads();
    if (threadIdx.x == 0)
        __hip_atomic_fetch_add(c, 1u, __ATOMIC_RELEASE, __HIP_MEMORY_SCOPE_AGENT);
}
__device__ __forceinline__ void gbar_wait(u32* c, u32 n) {
    if (threadIdx.x == 0) {
        while (__hip_atomic_load(c, __ATOMIC_ACQUIRE, __HIP_MEMORY_SCOPE_AGENT) < n)
            __builtin_amdgcn_s_sleep(2);
    }
    __syncthreads();
    __threadfence();
}

// ================== MONO KERNEL: prep + qkv + fused, 2 software barriers ==================
#define PSTR 520   // srow16 row stride (u16): 512 + 8 pad
#define YSTR 264   // y16 row stride (u16): 256 + 8 pad
__global__ __launch_bounds__(512, 4) void mono_kernel(
    const float* __restrict__ x, const float* __restrict__ area, const float* __restrict__ co,
    const float* __restrict__ Wq, const float* __restrict__ bq,
    const float* __restrict__ Wk, const float* __restrict__ bk,
    const float* __restrict__ Wv, const float* __restrict__ bv,
    const float* __restrict__ We1, const float* __restrict__ be1,
    const float* __restrict__ We2, const float* __restrict__ be2,
    const float* __restrict__ Wo, const float* __restrict__ bo,
    const float* __restrict__ g_ot, const float* __restrict__ b_ot,
    const float* __restrict__ g1, const float* __restrict__ b1,
    const float* __restrict__ g2, const float* __restrict__ b2,
    u16* __restrict__ xb, u16* __restrict__ wb,
    u16* __restrict__ qb, u16* __restrict__ kb, u16* __restrict__ vt,
    u32* __restrict__ bar, float* __restrict__ out)
{
    const int tid = threadIdx.x;
    const int lane = tid & 63, w = tid >> 6;
    const int m = lane & 15, koff = (lane >> 4) * 8;
    const int g = lane >> 4, c = lane & 15;
    const int hP = tid & 255, half = tid >> 8;

    // XCD-aware bijective swizzle for phase C (512 = 8*64, exact)
    const int bsw = (blockIdx.x & 7) * 64 + (blockIdx.x >> 3);
    const int b = bsw >> 7;
    const int i0 = (bsw & 127) << 2;

    __shared__ float histS[1024], histB[1024];
    __shared__ float pvbuf[1024];
    __shared__ u16 srow16[16 * PSTR];
    __shared__ u16 y16[16 * YSTR];
    __shared__ float4 red8b[16];
    __shared__ float sBaseS[4], sBaseB[4], redA[8], redB[8];

    // ---- phase-C preloads that depend only on kernel inputs ----
    float cov[4];
#pragma unroll
    for (int t = 0; t < 4; ++t)
        cov[t] = co[(size_t)(i0 + g) * NN + (w * 4 + t) * 16 + c];
    float xv[TI];
#pragma unroll
    for (int ti = 0; ti < TI; ++ti)
        xv[ti] = x[(size_t)(b * NN + i0 + ti) * ND + hP];
    const float bov  = bo[hP];
    const float g1v  = g1[hP],  b1v  = b1[hP];
    const float gotv = g_ot[hP], botv = b_ot[hP];
    const float g2v  = g2[hP],  b2v  = b2[hP];
    const float be2f = be2[0];

    // ================= PHASE A0: fp32 -> bf16 (x, Wq|Wk|Wv|Wo) =================
    {
        const int gtid = blockIdx.x * 512 + tid;      // 262144 threads
        const int idx4 = gtid * 4;                    // covers 786432 floats
        if (idx4 < 786432) {
            const float* src; u16* dst; int off;
            if (idx4 < 524288) { src = x; dst = xb; off = idx4; }
            else {
                int u = idx4 - 524288;
                int which = u >> 16; off = u & 65535;
                src = (which == 0) ? Wq : (which == 1) ? Wk : (which == 2) ? Wv : Wo;
                dst = wb + which * 65536;
            }
            float4 f = *(const float4*)(src + off);
            u32 lo = (u32)bfq(f.x) | ((u32)bfq(f.y) << 16);
            u32 hi = (u32)bfq(f.z) | ((u32)bfq(f.w) << 16);
            *(uint2*)(dst + off) = make_uint2(lo, hi);
        }
    }
    gbar_arrive(bar);        // barrier 1 arrive (xb/wb flushed)

    // ===== bar1 shadow: LDS zero + gate histogram + scan (input-only work) =====
    histS[tid] = 0.f; histS[tid + 512] = 0.f;
    histB[tid] = 0.f; histB[tid + 512] = 0.f;
    {
        u32* s32 = (u32*)srow16;
        for (int i = tid; i < 4160; i += 512) s32[i] = 0u;
        u32* y32 = (u32*)y16;
        for (int i = tid; i < 2112; i += 512) y32[i] = 0u;
    }
    __syncthreads();
    {
        const int s = tid >> 7, h0 = tid & 127;
        const float a = area[b * NN + i0 + s];
        float baS = 0.f, baB = 0.f;
#pragma unroll
        for (int k = 0; k < 2; ++k) {
            const int h = h0 + 128 * k;
            const float w10 = We1[2 * h], w11 = We1[2 * h + 1];
            const float w2v = We2[h], be1v = be1[h];
            const float al = fmaf(a, w10, be1v);
            const float sl = w11 * w2v, bb = al * w2v;
            if (w11 == 0.f) {
                if (al > 0.f) baB += bb;
            } else {
                float tt = -al / w11;
                if (w11 > 0.f) {
                    if (tt <= 0.f)      { baS += sl; baB += bb; }
                    else if (tt < 1.f) {
                        int u = (int)(tt * 256.f); u = u > 255 ? 255 : u;
                        atomicAdd(&histS[s * 256 + u], sl);
                        atomicAdd(&histB[s * 256 + u], bb);
                    }
                } else {
                    if (tt >= 1.f)      { baS += sl; baB += bb; }
                    else if (tt > 0.f) {
                        baS += sl; baB += bb;
                        int u = (int)(tt * 256.f); u = u > 255 ? 255 : u;
                        atomicAdd(&histS[s * 256 + u], -sl);
                        atomicAdd(&histB[s * 256 + u], -bb);
                    }
                }
            }
        }
        float rS = waveReduceSum(baS), rB = waveReduceSum(baB);
        if (lane == 0) { redA[w] = rS; redB[w] = rB; }
    }
    __syncthreads();
    if (tid < 4) {
        sBaseS[tid] = redA[2 * tid] + redA[2 * tid + 1];
        sBaseB[tid] = redB[2 * tid] + redB[2 * tid + 1];
    }
    {   // in-place inclusive scan of the histograms
        const int s = w & 3;
        float* hp = (w < 4) ? histS : histB;
        float b0 = hp[s * 256 + 4 * lane + 0];
        float b1 = hp[s * 256 + 4 * lane + 1];
        float b2 = hp[s * 256 + 4 * lane + 2];
        float b3 = hp[s * 256 + 4 * lane + 3];
        float p0 = b0, p1 = p0 + b1, p2 = p1 + b2, p3 = p2 + b3;
        float incl = p3;
#pragma unroll
        for (int off = 1; off < 64; off <<= 1) {
            float t = __shfl_up(incl, off);
            if (lane >= off) incl += t;
        }
        float excl = incl - p3;
        hp[s * 256 + 4 * lane + 0] = p0 + excl;
        hp[s * 256 + 4 * lane + 1] = p1 + excl;
        hp[s * 256 + 4 * lane + 2] = p2 + excl;
        hp[s * 256 + 4 * lane + 3] = p3 + excl;
    }
    gbar_wait(bar, NBLK);    // barrier 1 wait (xb/wb valid; scan visible via its sync)

    // ================= PHASE A1: q/k/v projections from bf16 =================
    // 6144 wave-jobs over 4096 waves: job = rowTile(0..127) | colJob(0..47)<<7.
    {
        const int wid = blockIdx.x * 8 + w;
        for (int job = wid; job < 6144; job += 4096) {
            const int rowTile = job & 127;
            const int colJob  = job >> 7;
            const int which   = colJob >> 4;
            const int oc0     = (colJob & 15) << 4;
            const int r0      = rowTile << 4;
            const float* bia = (which == 0) ? bq : (which == 1) ? bk : bv;

            const u16* Ap = xb + (size_t)(r0 + m) * 256 + koff;
            const u16* Bp = wb + which * 65536 + (size_t)(oc0 + m) * 256 + koff;

            f32x4 acc = {0.f, 0.f, 0.f, 0.f};
#pragma unroll
            for (int ks = 0; ks < 8; ++ks) {
                short8 a  = *(const short8*)(Ap + ks * 32);
                short8 bb = *(const short8*)(Bp + ks * 32);
                acc = __builtin_amdgcn_mfma_f32_16x16x32_bf16(a, bb, acc, 0, 0, 0);
            }
            const int oc = oc0 + m;
            const float bias = bia[oc];
            const int rbase = r0 + (lane >> 4) * 4;
#pragma unroll
            for (int reg = 0; reg < 4; ++reg) {
                int R = rbase + reg;
                u16 val = bfq(acc[reg] + bias);
                if (which == 0)      qb[(size_t)R * 256 + oc] = val;
                else if (which == 1) kb[(size_t)R * 256 + oc] = val;
                else                 vt[((size_t)(R >> 9) * 256 + oc) * 512 + (R & 511)] = val;
            }
        }
    }
    gbar_arrive(bar + 16);   // barrier 2
    gbar_wait(bar + 16, NBLK);

    // ================= PHASE C: fused S-GEMM + attention + LN stack =================
    // ---- S = Q.K^T for rows i0..i0+3 (wave w owns j-tiles 4w..4w+3) ----
    f32x4 sacc[4];
    {
        const u16* Ap    = qb + (size_t)(b * 512 + i0 + m) * 256 + koff;
        const u16* Kbase = kb + (size_t)(b * 512 + m) * 256 + koff;
        short8 afr[8];
#pragma unroll
        for (int ks = 0; ks < 8; ++ks) afr[ks] = *(const short8*)(Ap + ks * 32);
#pragma unroll
        for (int t = 0; t < 4; ++t) {
            const u16* Bp = Kbase + (size_t)(w * 4 + t) * 16 * 256;
            f32x4 acc = {0.f, 0.f, 0.f, 0.f};
#pragma unroll
            for (int ks = 0; ks < 8; ++ks) {
                short8 bb = *(const short8*)(Bp + ks * 32);
                acc = __builtin_amdgcn_mfma_f32_16x16x32_bf16(afr[ks], bb, acc, 0, 0, 0);
            }
            sacc[t] = acc;
        }
    }

    // ---- apply gate (hist/sBase ready since bar1): all 64 lanes ----
    {
#pragma unroll
        for (int t = 0; t < 4; ++t) {
            const int j = (w * 4 + t) * 16 + c;
            float s0 = __shfl(sacc[t][0], c);
            float s1 = __shfl(sacc[t][1], c);
            float s2 = __shfl(sacc[t][2], c);
            float s3 = __shfl(sacc[t][3], c);
            float sv = (g == 0) ? s0 : (g == 1) ? s1 : (g == 2) ? s2 : s3;
            float cc = cov[t];
            int u = (int)(cc * 256.f); u = u > 255 ? 255 : u;
            float Sg = sBaseS[g] + histS[g * 256 + u];
            float Bg = sBaseB[g] + histB[g * 256 + u];
            float e = fmaf(cc, Sg, Bg) + be2f;
            float ew = 1.f / (1.f + __expf(-e));
            srow16[g * PSTR + j] = bfq(__expf(sv * 0.0625f * ew));
        }
    }
    __syncthreads();

    // ---- PV via MFMA ----
    {
        const int t0 = 2 * w, t1 = 2 * w + 1;
        const u16* B0p = vt + ((size_t)(b * 256 + t0 * 16 + m)) * 512 + koff;
        const u16* B1p = vt + ((size_t)(b * 256 + t1 * 16 + m)) * 512 + koff;
        const u16* Arow = srow16 + m * PSTR + koff;
        f32x4 acc0 = {0.f, 0.f, 0.f, 0.f}, acc1 = {0.f, 0.f, 0.f, 0.f};
#pragma unroll
        for (int ks = 0; ks < 16; ++ks) {
            short8 a  = *(const short8*)(Arow + ks * 32);
            short8 b0 = *(const short8*)(B0p + ks * 32);
            short8 b1 = *(const short8*)(B1p + ks * 32);
            acc0 = __builtin_amdgcn_mfma_f32_16x16x32_bf16(a, b0, acc0, 0, 0, 0);
            acc1 = __builtin_amdgcn_mfma_f32_16x16x32_bf16(a, b1, acc1, 0, 0, 0);
        }
        if (lane < 16) {
#pragma unroll
            for (int reg = 0; reg < 4; ++reg) {
                pvbuf[reg * 256 + t0 * 16 + lane] = acc0[reg];
                pvbuf[reg * 256 + t1 * 16 + lane] = acc1[reg];
            }
        }
        __syncthreads();
    }

    // ---- LN1 -> y1 bf16 ----
    float4 sa, sb;
    float accv[TI];
#pragma unroll
    for (int ti = 0; ti < TI; ++ti) {
        accv[ti] = (half == 0) ? pvbuf[ti * 256 + hP] : 0.f;
        ((float*)&sa)[ti] = accv[ti];
        ((float*)&sb)[ti] = accv[ti] * accv[ti];
    }
    blockReduce8(sa, sb, red8b);
    if (half == 0) {
#pragma unroll
        for (int ti = 0; ti < TI; ++ti) {
            float mean = ((const float*)&sa)[ti] * (1.f / 256.f);
            float var = fmaxf(((const float*)&sb)[ti] * (1.f / 256.f) - mean * mean, 0.f);
            y16[ti * YSTR + hP] = bfq((accv[ti] - mean) * rsqrtf(var + 1e-5f) * g1v + b1v);
        }
    }
    __syncthreads();

    // ---- Wo via MFMA (wob = wb + 3*65536, bf16) ----
    {
        const u16* wob = wb + 3 * 65536;
        const int t0 = 2 * w, t1 = 2 * w + 1;
        const u16* B0p = wob + (size_t)(t0 * 16 + m) * 256 + koff;
        const u16* B1p = wob + (size_t)(t1 * 16 + m) * 256 + koff;
        const u16* Arow = y16 + m * YSTR + koff;
        f32x4 acc0 = {0.f, 0.f, 0.f, 0.f}, acc1 = {0.f, 0.f, 0.f, 0.f};
#pragma unroll
        for (int ks = 0; ks < 8; ++ks) {
            short8 a  = *(const short8*)(Arow + ks * 32);
            short8 b0 = *(const short8*)(B0p + ks * 32);
            short8 b1 = *(const short8*)(B1p + ks * 32);
            acc0 = __builtin_amdgcn_mfma_f32_16x16x32_bf16(a, b0, acc0, 0, 0, 0);
            acc1 = __builtin_amdgcn_mfma_f32_16x16x32_bf16(a, b1, acc1, 0, 0, 0);
        }
        if (lane < 16) {
#pragma unroll
            for (int reg = 0; reg < 4; ++reg) {
                pvbuf[reg * 256 + t0 * 16 + lane] = acc0[reg];
                pvbuf[reg * 256 + t1 * 16 + lane] = acc1[reg];
            }
        }
        __syncthreads();
    }

    // ---- + bo, LN(g_ot,b_ot) + relu ----
    float acc2[TI];
#pragma unroll
    for (int ti = 0; ti < TI; ++ti) {
        acc2[ti] = (half == 0) ? pvbuf[ti * 256 + hP] + bov : 0.f;
        ((float*)&sa)[ti] = acc2[ti];
        ((float*)&sb)[ti] = acc2[ti] * acc2[ti];
    }
    blockReduce8(sa, sb, red8b);
    float z[TI];
#pragma unroll
    for (int ti = 0; ti < TI; ++ti) {
        float mean = ((const float*)&sa)[ti] * (1.f / 256.f);
        float var = fmaxf(((const float*)&sb)[ti] * (1.f / 256.f) - mean * mean, 0.f);
        z[ti] = fmaxf((acc2[ti] - mean) * rsqrtf(var + 1e-5f) * gotv + botv, 0.f);
    }

    // ---- residual + LN2 + store ----
    float tt[TI];
#pragma unroll
    for (int ti = 0; ti < TI; ++ti) {
        tt[ti] = (half == 0) ? z[ti] + xv[ti] : 0.f;
        ((float*)&sa)[ti] = tt[ti]; ((float*)&sb)[ti] = tt[ti] * tt[ti];
    }
    blockReduce8(sa, sb, red8b);
    if (half == 0) {
#pragma unroll
        for (int ti = 0; ti < TI; ++ti) {
            float mean = ((const float*)&sa)[ti] * (1.f / 256.f);
            float var = fmaxf(((const float*)&sb)[ti] * (1.f / 256.f) - mean * mean, 0.f);
            float o = (tt[ti] - mean) * rsqrtf(var + 1e-5f) * g2v + b2v;
            out[(size_t)(b * NN + i0 + ti) * NH + hP] = o;
        }
    }
}

extern "C" void kernel_launch(void* const* d_in, const int* in_sizes, int n_in,
                              void* d_out, int out_size, void* d_ws, size_t ws_size,
                              hipStream_t stream) {
    const float* x    = (const float*)d_in[0];
    const float* area = (const float*)d_in[1];
    const float* co   = (const float*)d_in[2];
    const float* Wq   = (const float*)d_in[3];
    const float* bq   = (const float*)d_in[4];
    const float* Wk   = (const float*)d_in[5];
    const float* bk   = (const float*)d_in[6];
    const float* Wv   = (const float*)d_in[7];
    const float* bv   = (const float*)d_in[8];
    const float* We1  = (const float*)d_in[9];
    const float* be1  = (const float*)d_in[10];
    const float* We2  = (const float*)d_in[11];
    const float* be2  = (const float*)d_in[12];
    const float* Wo   = (const float*)d_in[13];
    const float* bo   = (const float*)d_in[14];
    const float* g_ot = (const float*)d_in[15];
    const float* b_ot = (const float*)d_in[16];
    const float* g1   = (const float*)d_in[17];
    const float* b1   = (const float*)d_in[18];
    const float* g2   = (const float*)d_in[19];
    const float* b2   = (const float*)d_in[20];

    u16*  xb  = (u16*)d_ws;                      // 1 MB    bf16 x [row][d]
    u16*  wb  = xb + (size_t)2048 * 256;         // 512 KB  bf16 [Wq|Wk|Wv|Wo]
    u16*  qb  = wb + (size_t)4 * 65536;          // 1 MB    bf16 q
    u16*  kb  = qb + (size_t)2048 * 256;         // 1 MB    bf16 k
    u16*  vt  = kb + (size_t)2048 * 256;         // 1 MB    bf16 v transposed
    u32*  bar = (u32*)((char*)d_ws + ((size_t)32 << 20));  // barrier counters @ +32MB
    float* outp = (float*)d_out;

    hipMemsetAsync(bar, 0, 128, stream);
    mono_kernel<<<NBLK, 512, 0, stream>>>(x, area, co, Wq, bq, Wk, bk, Wv, bv,
                                          We1, be1, We2, be2, Wo, bo,
                                          g_ot, b_ot, g1, b1, g2, b2,
                                          xb, wb, qb, kb, vt, bar, outp);
}

// Round 8
// 198.395 us; speedup vs baseline: 1.8323x; 1.8323x over previous
//
#include <hip/hip_runtime.h>

typedef unsigned short u16;
typedef unsigned int u32;

#define NB 4
#define NN 512
#define ND 256
#define NH 256
#define TI 2

typedef __attribute__((ext_vector_type(8))) short short8;
typedef __attribute__((ext_vector_type(4))) float f32x4;

__device__ __forceinline__ u16 bfq(float f) {
    u32 t; __builtin_memcpy(&t, &f, 4);
    u32 r = (t + 0x7FFFu + ((t >> 16) & 1u)) >> 16;
    return (u16)r;
}

__device__ __forceinline__ float waveReduceSum(float v) {
#pragma unroll
    for (int o = 32; o > 0; o >>= 1) v += __shfl_down(v, o);
    return v;
}

// block-wide sum-reduce of TWO float4s (8 values) across 8 waves; 2 barriers total.
__device__ __forceinline__ void blockReduce8(float4& va, float4& vb, float4* red) {
#pragma unroll
    for (int o = 32; o > 0; o >>= 1) {
        va.x += __shfl_down(va.x, o); va.y += __shfl_down(va.y, o);
        va.z += __shfl_down(va.z, o); va.w += __shfl_down(va.w, o);
        vb.x += __shfl_down(vb.x, o); vb.y += __shfl_down(vb.y, o);
        vb.z += __shfl_down(vb.z, o); vb.w += __shfl_down(vb.w, o);
    }
    int wid = threadIdx.x >> 6;
    __syncthreads();
    if ((threadIdx.x & 63) == 0) { red[2 * wid] = va; red[2 * wid + 1] = vb; }
    __syncthreads();
    float4 ra = red[0], rb = red[1];
#pragma unroll
    for (int w = 1; w < 8; ++w) {
        float4 ua = red[2 * w], ub = red[2 * w + 1];
        ra.x += ua.x; ra.y += ua.y; ra.z += ua.z; ra.w += ua.w;
        rb.x += ub.x; rb.y += ub.y; rb.z += ub.z; rb.w += ub.w;
    }
    va = ra; vb = rb;
}

// ---------------- K1: prep + q/k/v projections fused via LDS-staged bf16 ----------------
// grid (32, 48), 256 thr. Block (bx, by): stages x rows [64bx,64bx+64) and W rows
// [16*(by&15), +16) fp32->bf16 ONCE into padded LDS, then MFMAs from LDS.
// Same bfq rounding + MFMA order as prep+qkv pair -> bit-identical outputs.
#define XSTR 264   // LDS row stride (u16): 256 + 8 pad (2-way-free banks)
__global__ __launch_bounds__(256) void qkv_mfma(
    const float* __restrict__ x,
    const float* __restrict__ Wq, const float* __restrict__ bq,
    const float* __restrict__ Wk, const float* __restrict__ bk,
    const float* __restrict__ Wv, const float* __restrict__ bv,
    u16* __restrict__ qb, u16* __restrict__ kb, u16* __restrict__ vt)
{
    const int tid = threadIdx.x;
    const int lane = tid & 63, wave = tid >> 6;
    const int which = blockIdx.y >> 4;
    const int out0 = blockIdx.y * 16;
    const int wr0 = (blockIdx.y & 15) * 16;           // W row base
    const int r0b = blockIdx.x * 64;                  // x row base for this block
    const float* W   = (which == 0) ? Wq : (which == 1) ? Wk : Wv;
    const float* bia = (which == 0) ? bq : (which == 1) ? bk : bv;

    __shared__ u16 xs[64 * XSTR];
    __shared__ u16 ws[16 * XSTR];

    // ---- stage x tile: 4096 float4s over 256 threads ----
#pragma unroll
    for (int i = 0; i < 16; ++i) {
        const int f = i * 256 + tid;                  // float4 index
        const int row = f >> 6, col4 = f & 63;
        float4 v = *(const float4*)(x + (size_t)(r0b + row) * 256 + col4 * 4);
        u32 lo = (u32)bfq(v.x) | ((u32)bfq(v.y) << 16);
        u32 hi = (u32)bfq(v.z) | ((u32)bfq(v.w) << 16);
        *(uint2*)(xs + row * XSTR + col4 * 4) = make_uint2(lo, hi);
    }
    // ---- stage W tile: 1024 float4s ----
#pragma unroll
    for (int i = 0; i < 4; ++i) {
        const int f = i * 256 + tid;
        const int row = f >> 6, col4 = f & 63;
        float4 v = *(const float4*)(W + (size_t)(wr0 + row) * 256 + col4 * 4);
        u32 lo = (u32)bfq(v.x) | ((u32)bfq(v.y) << 16);
        u32 hi = (u32)bfq(v.z) | ((u32)bfq(v.w) << 16);
        *(uint2*)(ws + row * XSTR + col4 * 4) = make_uint2(lo, hi);
    }
    __syncthreads();

    const int m = lane & 15, koff = (lane >> 4) * 8;
    const u16* Ap = xs + (wave * 16 + m) * XSTR + koff;
    const u16* Bp = ws + m * XSTR + koff;

    f32x4 acc = {0.f, 0.f, 0.f, 0.f};
#pragma unroll
    for (int ks = 0; ks < 8; ++ks) {
        short8 a  = *(const short8*)(Ap + ks * 32);
        short8 bb = *(const short8*)(Bp + ks * 32);
        acc = __builtin_amdgcn_mfma_f32_16x16x32_bf16(a, bb, acc, 0, 0, 0);
    }

    const int oc = (out0 + m) & 255;
    const float bias = bia[oc];
    const int rbase = r0b + wave * 16 + (lane >> 4) * 4;
#pragma unroll
    for (int reg = 0; reg < 4; ++reg) {
        int R = rbase + reg;
        u16 val = bfq(acc[reg] + bias);
        if (which == 0)      qb[(size_t)R * 256 + oc] = val;
        else if (which == 1) kb[(size_t)R * 256 + oc] = val;
        else                 vt[((size_t)(R >> 9) * 256 + oc) * 512 + (R & 511)] = val;
    }
}

// ---------------- K2: fused S-GEMM + gate + attention + LN stack, TI=2 ----------------
// 1024 blocks (4/CU, full occupancy). Per-phase work halved vs TI=4; phase count same.
#define PSTR 520   // srow16 row stride (u16)
#define YSTR 264   // y16 row stride (u16)
__global__ __launch_bounds__(512, 4) void fused_kernel(
    const float* __restrict__ x, const float* __restrict__ area, const float* __restrict__ co,
    const float* __restrict__ We1, const float* __restrict__ be1,
    const float* __restrict__ We2, const float* __restrict__ be2,
    const u16* __restrict__ wob_dummy, const float* __restrict__ bo,
    const float* __restrict__ g_ot, const float* __restrict__ b_ot,
    const float* __restrict__ g1, const float* __restrict__ b1,
    const float* __restrict__ g2, const float* __restrict__ b2,
    const u16* __restrict__ qb, const u16* __restrict__ kb,
    const u16* __restrict__ vt, const u16* __restrict__ wob,
    float* __restrict__ out)
{
    const int tid = threadIdx.x;
    // XCD-aware bijective swizzle (1024 = 8*128, exact)
    const int bsw = (blockIdx.x & 7) * 128 + (blockIdx.x >> 3);
    const int b = bsw >> 8;
    const int i0 = (bsw & 255) << 1;
    const int lane = tid & 63, w = tid >> 6;
    const int g = lane >> 4, c = lane & 15;
    const int r = g & 1, hsel = g >> 1;            // row 0/1, tile-half 0/1
    const int hP = tid & 255, half = tid >> 8;

    __shared__ float histS[512], histB[512];
    __shared__ float pvbuf[512];
    __shared__ u16 srow16[16 * PSTR];     // P bf16, rows 2..15 zero
    __shared__ u16 y16[16 * YSTR];        // y1 bf16, rows 2..15 zero
    __shared__ float4 red8b[16];
    __shared__ float sBaseS[2], sBaseB[2], redA[8], redB[8];

    // ---- long-latency preloads ----
    const int m = lane & 15, koff = (lane >> 4) * 8;
    const u16* Ap    = qb + (size_t)(b * 512 + i0 + m) * 256 + koff;
    const u16* Kbase = kb + (size_t)(b * 512 + m) * 256 + koff;

    short8 afr[8];
#pragma unroll
    for (int ks = 0; ks < 8; ++ks) afr[ks] = *(const short8*)(Ap + ks * 32);

    float cov[2];
#pragma unroll
    for (int t = 0; t < 2; ++t)
        cov[t] = co[(size_t)(i0 + r) * NN + (w * 4 + 2 * t + hsel) * 16 + c];

    float xv[TI];
#pragma unroll
    for (int ti = 0; ti < TI; ++ti)
        xv[ti] = x[(size_t)(b * NN + i0 + ti) * ND + hP];

    const float bov  = bo[hP];
    const float g1v  = g1[hP],  b1v  = b1[hP];
    const float gotv = g_ot[hP], botv = b_ot[hP];
    const float g2v  = g2[hP],  b2v  = b2[hP];
    const float be2f = be2[0];

    // ---- init: zero hist + bf16 staging buffers ----
    histS[tid & 511] = 0.f; histB[tid & 511] = 0.f;
    {
        u32* s32 = (u32*)srow16;                 // 4160 u32
        for (int i = tid; i < 4160; i += 512) s32[i] = 0u;
        u32* y32 = (u32*)y16;                    // 2112 u32
        for (int i = tid; i < 2112; i += 512) y32[i] = 0u;
    }
    __syncthreads();

    // ---- gate: scatter hinge deltas; set s = tid>>8 (row), one h per thread ----
    {
        const int s = tid >> 8, h = tid & 255;
        const float a = area[b * NN + i0 + s];
        float baS = 0.f, baB = 0.f;
        {
            const float w10 = We1[2 * h], w11 = We1[2 * h + 1];
            const float w2v = We2[h], be1v = be1[h];
            const float al = fmaf(a, w10, be1v);
            const float sl = w11 * w2v, bb = al * w2v;
            if (w11 == 0.f) {
                if (al > 0.f) baB += bb;
            } else {
                float tt = -al / w11;
                if (w11 > 0.f) {
                    if (tt <= 0.f)      { baS += sl; baB += bb; }
                    else if (tt < 1.f) {
                        int u = (int)(tt * 256.f); u = u > 255 ? 255 : u;
                        atomicAdd(&histS[s * 256 + u], sl);
                        atomicAdd(&histB[s * 256 + u], bb);
                    }
                } else {
                    if (tt >= 1.f)      { baS += sl; baB += bb; }
                    else if (tt > 0.f) {
                        baS += sl; baB += bb;
                        int u = (int)(tt * 256.f); u = u > 255 ? 255 : u;
                        atomicAdd(&histS[s * 256 + u], -sl);
                        atomicAdd(&histB[s * 256 + u], -bb);
                    }
                }
            }
        }
        float rS = waveReduceSum(baS), rB = waveReduceSum(baB);
        if (lane == 0) { redA[w] = rS; redB[w] = rB; }
    }

    // ---- S = Q.K^T (wave w owns j-tiles 4w..4w+3); rows 2..15 garbage, unused ----
    f32x4 sacc[4];
    {
#pragma unroll
        for (int t = 0; t < 4; ++t) {
            const u16* Bp = Kbase + (size_t)(w * 4 + t) * 16 * 256;
            f32x4 acc = {0.f, 0.f, 0.f, 0.f};
#pragma unroll
            for (int ks = 0; ks < 8; ++ks) {
                short8 bb = *(const short8*)(Bp + ks * 32);
                acc = __builtin_amdgcn_mfma_f32_16x16x32_bf16(afr[ks], bb, acc, 0, 0, 0);
            }
            sacc[t] = acc;
        }
    }
    __syncthreads();
    if (tid < 2) {
        sBaseS[tid] = redA[4 * tid] + redA[4 * tid + 1] + redA[4 * tid + 2] + redA[4 * tid + 3];
        sBaseB[tid] = redB[4 * tid] + redB[4 * tid + 1] + redB[4 * tid + 2] + redB[4 * tid + 3];
    }

    // ---- in-place inclusive scan: waves 0-1 scan histS sets 0-1; waves 4-5 histB ----
    {
        const int s = w & 3;
        if (s < 2) {
            float* hp = (w < 4) ? histS : histB;
            float b0 = hp[s * 256 + 4 * lane + 0];
            float b1 = hp[s * 256 + 4 * lane + 1];
            float b2 = hp[s * 256 + 4 * lane + 2];
            float b3 = hp[s * 256 + 4 * lane + 3];
            float p0 = b0, p1 = p0 + b1, p2 = p1 + b2, p3 = p2 + b3;
            float incl = p3;
#pragma unroll
            for (int off = 1; off < 64; off <<= 1) {
                float t = __shfl_up(incl, off);
                if (lane >= off) incl += t;
            }
            float excl = incl - p3;
            hp[s * 256 + 4 * lane + 0] = p0 + excl;
            hp[s * 256 + 4 * lane + 1] = p1 + excl;
            hp[s * 256 + 4 * lane + 2] = p2 + excl;
            hp[s * 256 + 4 * lane + 3] = p3 + excl;
        }
    }
    __syncthreads();

    // ---- apply gate: thread (g,c) -> row r=g&1, tiles 2t+hsel ----
    // FIX vs r7: shfl operands use ONLY lane-uniform indices (te/to); per-lane
    // select (hsel, r) happens AFTER the shuffle. (shfl returns the SOURCE
    // lane's value of the operand expression; a per-lane index inside the
    // operand reads the wrong tile.)
    {
#pragma unroll
        for (int t = 0; t < 2; ++t) {
            const int te = 2 * t, to = 2 * t + 1;
            float e0 = __shfl(sacc[te][0], c);
            float e1 = __shfl(sacc[te][1], c);
            float o0 = __shfl(sacc[to][0], c);
            float o1 = __shfl(sacc[to][1], c);
            float sv = hsel ? (r ? o1 : o0) : (r ? e1 : e0);
            const int tt = te + hsel;
            const int j = (w * 4 + tt) * 16 + c;
            float cc = cov[t];
            int u = (int)(cc * 256.f); u = u > 255 ? 255 : u;
            float Sg = sBaseS[r] + histS[r * 256 + u];
            float Bg = sBaseB[r] + histB[r * 256 + u];
            float e = fmaf(cc, Sg, Bg) + be2f;
            float ew = 1.f / (1.f + __expf(-e));
            srow16[r * PSTR + j] = bfq(__expf(sv * 0.0625f * ew));
        }
    }
    __syncthreads();

    // ---- PV via MFMA: wave w owns h-tiles 2w, 2w+1 ----
    {
        const int t0 = 2 * w, t1 = 2 * w + 1;
        const u16* B0p = vt + ((size_t)(b * 256 + t0 * 16 + m)) * 512 + koff;
        const u16* B1p = vt + ((size_t)(b * 256 + t1 * 16 + m)) * 512 + koff;
        const u16* Arow = srow16 + m * PSTR + koff;
        f32x4 acc0 = {0.f, 0.f, 0.f, 0.f}, acc1 = {0.f, 0.f, 0.f, 0.f};
#pragma unroll
        for (int ks = 0; ks < 16; ++ks) {
            short8 a  = *(const short8*)(Arow + ks * 32);
            short8 b0 = *(const short8*)(B0p + ks * 32);
            short8 b1 = *(const short8*)(B1p + ks * 32);
            acc0 = __builtin_amdgcn_mfma_f32_16x16x32_bf16(a, b0, acc0, 0, 0, 0);
            acc1 = __builtin_amdgcn_mfma_f32_16x16x32_bf16(a, b1, acc1, 0, 0, 0);
        }
        if (lane < 16) {                 // rows 0..1 live in lanes 0..15, regs 0..1
#pragma unroll
            for (int reg = 0; reg < TI; ++reg) {
                pvbuf[reg * 256 + t0 * 16 + lane] = acc0[reg];
                pvbuf[reg * 256 + t1 * 16 + lane] = acc1[reg];
            }
        }
        __syncthreads();
    }

    // ---- LN1 -> y1 bf16 ----
    float4 sa = {0.f, 0.f, 0.f, 0.f}, sb = {0.f, 0.f, 0.f, 0.f};
    float accv[TI];
#pragma unroll
    for (int ti = 0; ti < TI; ++ti) {
        accv[ti] = (half == 0) ? pvbuf[ti * 256 + hP] : 0.f;
        ((float*)&sa)[ti] = accv[ti];
        ((float*)&sb)[ti] = accv[ti] * accv[ti];
    }
    blockReduce8(sa, sb, red8b);
    if (half == 0) {
#pragma unroll
        for (int ti = 0; ti < TI; ++ti) {
            float mean = ((const float*)&sa)[ti] * (1.f / 256.f);
            float var = fmaxf(((const float*)&sb)[ti] * (1.f / 256.f) - mean * mean, 0.f);
            y16[ti * YSTR + hP] = bfq((accv[ti] - mean) * rsqrtf(var + 1e-5f) * g1v + b1v);
        }
    }
    __syncthreads();

    // ---- Wo via MFMA (wob bf16) ----
    {
        const int t0 = 2 * w, t1 = 2 * w + 1;
        const u16* B0p = wob + (size_t)(t0 * 16 + m) * 256 + koff;
        const u16* B1p = wob + (size_t)(t1 * 16 + m) * 256 + koff;
        const u16* Arow = y16 + m * YSTR + koff;
        f32x4 acc0 = {0.f, 0.f, 0.f, 0.f}, acc1 = {0.f, 0.f, 0.f, 0.f};
#pragma unroll
        for (int ks = 0; ks < 8; ++ks) {
            short8 a  = *(const short8*)(Arow + ks * 32);
            short8 b0 = *(const short8*)(B0p + ks * 32);
            short8 b1 = *(const short8*)(B1p + ks * 32);
            acc0 = __builtin_amdgcn_mfma_f32_16x16x32_bf16(a, b0, acc0, 0, 0, 0);
            acc1 = __builtin_amdgcn_mfma_f32_16x16x32_bf16(a, b1, acc1, 0, 0, 0);
        }
        if (lane < 16) {
#pragma unroll
            for (int reg = 0; reg < TI; ++reg) {
                pvbuf[reg * 256 + t0 * 16 + lane] = acc0[reg];
                pvbuf[reg * 256 + t1 * 16 + lane] = acc1[reg];
            }
        }
        __syncthreads();
    }

    // ---- + bo, LN(g_ot,b_ot) + relu ----
    float acc2[TI];
#pragma unroll
    for (int ti = 0; ti < TI; ++ti) {
        acc2[ti] = (half == 0) ? pvbuf[ti * 256 + hP] + bov : 0.f;
        ((float*)&sa)[ti] = acc2[ti];
        ((float*)&sb)[ti] = acc2[ti] * acc2[ti];
    }
    blockReduce8(sa, sb, red8b);
    float z[TI];
#pragma unroll
    for (int ti = 0; ti < TI; ++ti) {
        float mean = ((const float*)&sa)[ti] * (1.f / 256.f);
        float var = fmaxf(((const float*)&sb)[ti] * (1.f / 256.f) - mean * mean, 0.f);
        z[ti] = fmaxf((acc2[ti] - mean) * rsqrtf(var + 1e-5f) * gotv + botv, 0.f);
    }

    // ---- residual + LN2 + store ----
    float tt2[TI];
#pragma unroll
    for (int ti = 0; ti < TI; ++ti) {
        tt2[ti] = (half == 0) ? z[ti] + xv[ti] : 0.f;
        ((float*)&sa)[ti] = tt2[ti]; ((float*)&sb)[ti] = tt2[ti] * tt2[ti];
    }
    blockReduce8(sa, sb, red8b);
    if (half == 0) {
#pragma unroll
        for (int ti = 0; ti < TI; ++ti) {
            float mean = ((const float*)&sa)[ti] * (1.f / 256.f);
            float var = fmaxf(((const float*)&sb)[ti] * (1.f / 256.f) - mean * mean, 0.f);
            float o = (tt2[ti] - mean) * rsqrtf(var + 1e-5f) * g2v + b2v;
            out[(size_t)(b * NN + i0 + ti) * NH + hP] = o;
        }
    }
}

// ---------------- K1b: Wo fp32 -> bf16 (tiny, overlaps qkv tail) ----------------
__global__ __launch_bounds__(256) void wo_prep(const float* __restrict__ Wo, u16* __restrict__ wob)
{
    const int idx4 = (blockIdx.x * 256 + threadIdx.x) * 4;   // 64 blocks cover 65536
    float4 f = *(const float4*)(Wo + idx4);
    u32 lo = (u32)bfq(f.x) | ((u32)bfq(f.y) << 16);
    u32 hi = (u32)bfq(f.z) | ((u32)bfq(f.w) << 16);
    *(uint2*)(wob + idx4) = make_uint2(lo, hi);
}

extern "C" void kernel_launch(void* const* d_in, const int* in_sizes, int n_in,
                              void* d_out, int out_size, void* d_ws, size_t ws_size,
                              hipStream_t stream) {
    const float* x    = (const float*)d_in[0];
    const float* area = (const float*)d_in[1];
    const float* co   = (const float*)d_in[2];
    const float* Wq   = (const float*)d_in[3];
    const float* bq   = (const float*)d_in[4];
    const float* Wk   = (const float*)d_in[5];
    const float* bk   = (const float*)d_in[6];
    const float* Wv   = (const float*)d_in[7];
    const float* bv   = (const float*)d_in[8];
    const float* We1  = (const float*)d_in[9];
    const float* be1  = (const float*)d_in[10];
    const float* We2  = (const float*)d_in[11];
    const float* be2  = (const float*)d_in[12];
    const float* Wo   = (const float*)d_in[13];
    const float* bo   = (const float*)d_in[14];
    const float* g_ot = (const float*)d_in[15];
    const float* b_ot = (const float*)d_in[16];
    const float* g1   = (const float*)d_in[17];
    const float* b1   = (const float*)d_in[18];
    const float* g2   = (const float*)d_in[19];
    const float* b2   = (const float*)d_in[20];

    u16*  qb  = (u16*)d_ws;                      // 1 MB   bf16 q [row][h]
    u16*  kb  = qb + (size_t)2048 * 256;         // 1 MB   bf16 k [row][h]
    u16*  vt  = kb + (size_t)2048 * 256;         // 1 MB   bf16 v TRANSPOSED [b][h][j]
    u16*  wob = vt + (size_t)2048 * 256;         // 128 KB bf16 Wo row-major

    wo_prep<<<64, 256, 0, stream>>>(Wo, wob);
    qkv_mfma<<<dim3(32, 48), 256, 0, stream>>>(x, Wq, bq, Wk, bk, Wv, bv, qb, kb, vt);
    fused_kernel<<<NB * NN / TI, 512, 0, stream>>>(x, area, co, We1, be1, We2, be2,
                                                   (const u16*)nullptr, bo,
                                                   g_ot, b_ot, g1, b1, g2, b2,
                                                   qb, kb, vt, wob, (float*)d_out);
}